// Round 7
// baseline (570.939 us; speedup 1.0000x reference)
//
#include <hip/hip_runtime.h>
#include <hip/hip_bf16.h>

#define HW1K  1048576    // 1024*1024

typedef float f4 __attribute__((ext_vector_type(4)));

__device__ __forceinline__ f4 relu4(f4 v) {
    v.x = fmaxf(v.x, 0.0f); v.y = fmaxf(v.y, 0.0f);
    v.z = fmaxf(v.z, 0.0f); v.w = fmaxf(v.w, 0.0f);
    return v;
}

// Weight-prep: OIHW -> wp[layer_base + (ci*9+ky*3+kx)*COUT + co] (co fastest:
// coalesced, f4-aligned over co; all layer bases mult of 4).
// Bases: L1@0(432) L2@432(4608) L3@5040(9216) L4@14256(18432) L5@32688(36864)
// L6@69552(55296), total 124848.
__global__ void prep_w(const float* __restrict__ w1, const float* __restrict__ w2,
                       const float* __restrict__ w3, const float* __restrict__ w4,
                       const float* __restrict__ w5, const float* __restrict__ w6,
                       float* __restrict__ wp) {
    int i = blockIdx.x * 256 + threadIdx.x;
    if (i >= 124848) return;
    const float* src; int base, cin, cout;
    if      (i < 432)   { src = w1; base = 0;     cin = 3;  cout = 16; }
    else if (i < 5040)  { src = w2; base = 432;   cin = 16; cout = 32; }
    else if (i < 14256) { src = w3; base = 5040;  cin = 32; cout = 32; }
    else if (i < 32688) { src = w4; base = 14256; cin = 32; cout = 64; }
    else if (i < 69552) { src = w5; base = 32688; cin = 64; cout = 64; }
    else                { src = w6; base = 69552; cin = 64; cout = 96; }
    int r  = i - base;
    int kk = r / cout;
    int co = r % cout;
    int ci = kk / 9;
    int t9 = kk % 9;
    wp[i] = src[(co * cin + ci) * 9 + t9];
}

// ---------------------------------------------------------------------------
// Strip conv layer, 512 threads, ci-split x2: half = tid>>8 computes ci4 range
// [half*CIN/8, (half+1)*CIN/8). Raw partials (no bias/relu) -> sOut (half 0)
// and sPart (half 1); combine() adds bias, applies relu.
// Thread (within half) = (cog -> 4 output ch, strip-slot -> 1x2 px strip).
// Strides SI=CIN+4, SO=COUT+4 (16B-aligned).
template <int WIN, int CIN, int COUT, int SPT>
__device__ __forceinline__ void layer_s2(const float* __restrict__ sIn, float* __restrict__ sOut,
                                         float* __restrict__ sPart, const float* __restrict__ wp) {
    constexpr int WOUT  = WIN - 2;
    constexpr int SI    = CIN + 4;
    constexpr int SO    = COUT + 4;
    constexpr int COG   = COUT / 4;
    constexpr int SLOTS = 256 / COG;
    constexpr int HSTR  = WOUT / 2;
    constexpr int NSTR  = WOUT * HSTR;
    constexpr int NCI4  = CIN / 8;          // ci4 iterations per half

    const int tid  = threadIdx.x;
    const int half = tid >> 8;
    const int t    = tid & 255;
    const int cog  = t % COG;
    const int co0  = cog * 4;
    const int ps   = t / COG;
    const int c40  = half * NCI4;

    float* dst = half ? sPart : sOut;

    #pragma unroll
    for (int s = 0; s < SPT; ++s) {
        int ss = ps + s * SLOTS;
        if (ss > NSTR - 1) ss = NSTR - 1;          // duplicates write same value
        const int row  = ss / HSTR;
        const int col2 = (ss % HSTR) * 2;
        const int base = (row * WIN + col2) * SI;

        f4 acc0 = {0.f, 0.f, 0.f, 0.f}, acc1 = {0.f, 0.f, 0.f, 0.f};

        for (int ci4 = c40; ci4 < c40 + NCI4; ++ci4) {
            f4 a[3][4];
            #pragma unroll
            for (int r = 0; r < 3; ++r)
                #pragma unroll
                for (int c = 0; c < 4; ++c)
                    a[r][c] = *(const f4*)(sIn + base + (r * WIN + c) * SI + ci4 * 4);
            #pragma unroll
            for (int cc = 0; cc < 4; ++cc) {
                #pragma unroll
                for (int ky = 0; ky < 3; ++ky) {
                    #pragma unroll
                    for (int kx = 0; kx < 3; ++kx) {
                        f4 w = *(const f4*)(wp + ((ci4 * 4 + cc) * 9 + ky * 3 + kx) * COUT + co0);
                        acc0 += w * a[ky][kx][cc];
                        acc1 += w * a[ky][kx + 1][cc];
                    }
                }
            }
        }
        const int opx = row * WOUT + col2;
        *(f4*)(dst + opx * SO + co0)       = acc0;
        *(f4*)(dst + (opx + 1) * SO + co0) = acc1;
    }
}

// Single-px variant (L5: 16 px x 16 cog = 256 per half), ci-split x2.
template <int WIN, int CIN, int COUT>
__device__ __forceinline__ void layer_p2(const float* __restrict__ sIn, float* __restrict__ sOut,
                                         float* __restrict__ sPart, const float* __restrict__ wp) {
    constexpr int WOUT = WIN - 2;
    constexpr int SI   = CIN + 4;
    constexpr int SO   = COUT + 4;
    constexpr int COG  = COUT / 4;
    constexpr int NCI4 = CIN / 8;

    const int tid  = threadIdx.x;
    const int half = tid >> 8;
    const int t    = tid & 255;
    const int cog  = t % COG;
    const int co0  = cog * 4;
    const int px   = t / COG;
    const int row  = px / WOUT, col = px % WOUT;
    const int base = (row * WIN + col) * SI;
    const int c40  = half * NCI4;

    f4 acc = {0.f, 0.f, 0.f, 0.f};

    for (int ci4 = c40; ci4 < c40 + NCI4; ++ci4) {
        f4 a[3][3];
        #pragma unroll
        for (int r = 0; r < 3; ++r)
            #pragma unroll
            for (int c = 0; c < 3; ++c)
                a[r][c] = *(const f4*)(sIn + base + (r * WIN + c) * SI + ci4 * 4);
        #pragma unroll
        for (int cc = 0; cc < 4; ++cc)
            #pragma unroll
            for (int k = 0; k < 9; ++k) {
                f4 w = *(const f4*)(wp + ((ci4 * 4 + cc) * 9 + k) * COUT + co0);
                acc += w * a[k / 3][k % 3][cc];
            }
    }
    float* dst = half ? sPart : sOut;
    *(f4*)(dst + px * SO + co0) = acc;
}

// Combine halves: out = relu(p0 + p1 + bias). In-place on sOut.
template <int NPX, int COUT, int RELU>
__device__ __forceinline__ void combine(float* __restrict__ sOut, const float* __restrict__ sPart,
                                        const float* __restrict__ bias) {
    constexpr int SO  = COUT + 4;
    constexpr int COG = COUT / 4;
    for (int i = threadIdx.x; i < NPX * COG; i += 512) {
        int px = i / COG, co0 = (i % COG) * 4;
        f4 v = *(const f4*)(sOut + px * SO + co0) + *(const f4*)(sPart + px * SO + co0)
             + *(const f4*)(bias + co0);
        if (RELU) v = relu4(v);
        *(f4*)(sOut + px * SO + co0) = v;
    }
}

// ---------------------------------------------------------------------------
// Fully fused per-grid-cell pipeline, block = (gx, gy, b), 512 threads.
// 14x14x3 cone -> conv1..6 (VALID 14->12->10->8->6->4->2) -> 2x2 pool ->
// c16[b][gy*16+gx][d][p]. Cone coords in [1,254]: padding never triggers.
__global__ __launch_bounds__(512, 4)
void fused_cone(const float* __restrict__ x, const float* __restrict__ wp,
                const float* __restrict__ b1, const float* __restrict__ b2,
                const float* __restrict__ b3, const float* __restrict__ b4,
                const float* __restrict__ b5, const float* __restrict__ b6,
                float* __restrict__ c16) {
    __shared__ float sA[3600];   // xin 784 / t2 3600 / t4 2448 / L6 part 1536
    __shared__ float sB[2880];   // t1 2880 / t3 2304 / t5 1088
    __shared__ float sC[3600];   // ci-split partials

    const int gx = blockIdx.x, gy = blockIdx.y, b = blockIdx.z;
    const float* xb = x + (size_t)b * 3 * HW1K;

    // xin: xlow cone [14*14][stride 4]; xlow[y][x] = avg of x rows 4y+1..4y+2,
    // cols 4x+1..4x+2 (exact bilinear 4x downsample).
    for (int i = threadIdx.x; i < 588; i += 512) {
        int c  = i % 3;
        int t  = i / 3;
        int xi = t % 14;
        int yi = t / 14;
        int ya = 16 * gy + 1 + yi;
        int xa = 16 * gx + 1 + xi;
        const float* p = xb + (size_t)c * HW1K + (4 * ya + 1) * 1024 + (4 * xa + 1);
        sA[t * 4 + c] = 0.25f * (p[0] + p[1] + p[1024] + p[1025]);
    }
    __syncthreads();

    // L1: CIN=3 (scalar act reads), 512 threads: cog=tid%4, 128 px-slots x2.
    // Bias+relu inline (no split). out t1 [144][20].
    {
        const int cog = threadIdx.x % 4, co0 = cog * 4, ps = threadIdx.x / 4;
        const f4 bs = *(const f4*)(b1 + co0);
        f4 acc[2]; int base[2], pxc[2];
        #pragma unroll
        for (int pp = 0; pp < 2; ++pp) {
            int px = ps + pp * 128; if (px > 143) px = 143;
            pxc[pp]  = px;
            base[pp] = ((px / 12) * 14 + (px % 12)) * 4;
            acc[pp]  = bs;
        }
        for (int ci = 0; ci < 3; ++ci) {
            #pragma unroll
            for (int k = 0; k < 9; ++k) {
                f4 w = *(const f4*)(wp + (ci * 9 + k) * 16 + co0);
                int off = ((k / 3) * 14 + (k % 3)) * 4 + ci;
                #pragma unroll
                for (int pp = 0; pp < 2; ++pp)
                    acc[pp] += w * sA[base[pp] + off];
            }
        }
        #pragma unroll
        for (int pp = 0; pp < 2; ++pp)
            *(f4*)(sB + pxc[pp] * 20 + co0) = relu4(acc[pp]);
    }
    __syncthreads();

    layer_s2<12, 16, 32, 2>(sB, sA, sC, wp + 432);   __syncthreads();
    combine<100, 32, 1>(sA, sC, b2);                 __syncthreads();  // t2 [100][36]
    layer_s2<10, 32, 32, 1>(sA, sB, sC, wp + 5040);  __syncthreads();
    combine<64, 32, 1>(sB, sC, b3);                  __syncthreads();  // t3 [64][36]
    layer_s2< 8, 32, 64, 2>(sB, sA, sC, wp + 14256); __syncthreads();
    combine<36, 64, 1>(sA, sC, b4);                  __syncthreads();  // t4 [36][68]
    layer_p2< 6, 64, 64>(sA, sB, sC, wp + 32688);    __syncthreads();
    combine<16, 64, 1>(sB, sC, b5);                  __syncthreads();  // t5 [16][68]

    // L6: CIN=64, COUT=96, WIN=4->WOUT=2 (4 px), ci-split x4 (quarters).
    // Active: 4*96 threads; raw partials -> sA [quarter][4px][96]; no relu.
    {
        const int q = threadIdx.x >> 7;
        const int r = threadIdx.x & 127;
        if (r < 96) {
            const int cog = r % 24, co0 = cog * 4, px = r / 24;
            const int base = ((px >> 1) * 4 + (px & 1)) * 68;
            f4 acc = {0.f, 0.f, 0.f, 0.f};
            for (int ci4 = q * 4; ci4 < q * 4 + 4; ++ci4) {
                f4 a[3][3];
                #pragma unroll
                for (int rr = 0; rr < 3; ++rr)
                    #pragma unroll
                    for (int c = 0; c < 3; ++c)
                        a[rr][c] = *(const f4*)(sB + base + (rr * 4 + c) * 68 + ci4 * 4);
                #pragma unroll
                for (int cc = 0; cc < 4; ++cc)
                    #pragma unroll
                    for (int k = 0; k < 9; ++k) {
                        f4 w = *(const f4*)(wp + 69552 + ((ci4 * 4 + cc) * 9 + k) * 96 + co0);
                        acc += w * a[k / 3][k % 3][cc];
                    }
            }
            *(f4*)(sA + q * 384 + px * 96 + co0) = acc;
        }
    }
    __syncthreads();

    // pool 2x2 (exact 16x bilinear downsample) + combine quarters + bias.
    if (threadIdx.x < 96) {
        const int ch = threadIdx.x;
        float v = 0.0f;
        #pragma unroll
        for (int q = 0; q < 4; ++q)
            #pragma unroll
            for (int px = 0; px < 4; ++px)
                v += sA[q * 384 + px * 96 + ch];
        v = 0.25f * v + b6[ch];
        int p = ch >> 3, d = ch & 7;
        c16[(size_t)b * 24576 + ((gy * 16 + gx) * 8 + d) * 12 + p] = v;
    }
}

// ---------------------------------------------------------------------------
// Fused guide + trilinear slice + affine + clip; 4 px per thread (float4).
// c16 layout: [b][gy*16+gx][d][p=12].
__global__ __launch_bounds__(256)
void slice_apply4(const float* __restrict__ x, const float* __restrict__ c16,
                  float* __restrict__ out) {
    int t = blockIdx.x * 256 + threadIdx.x;      // 0 .. 2*HW1K/4 - 1
    int po4 = t * 4;
    int b   = po4 >> 20;
    int po  = po4 & (HW1K - 1);
    int py  = po >> 10;
    int px0 = po & 1023;

    const float* xb = x + (size_t)b * 3 * HW1K;
    f4 rv  = *(const f4*)(xb + po);
    f4 gv  = *(const f4*)(xb + HW1K + po);
    f4 bv  = *(const f4*)(xb + 2 * HW1K + po);

    float ysf = (float)py * (15.0f / 1023.0f);
    int y0 = (int)floorf(ysf); int y1 = min(y0 + 1, 15);
    float wy = ysf - (float)y0;

    const float* gb = c16 + (size_t)b * 24576;
    f4 outv[3];

    #pragma unroll
    for (int s = 0; s < 4; ++s) {
        float r  = rv[s], g = gv[s], bl = bv[s];
        int   px = px0 + s;

        float gd = fminf(fmaxf(0.299f * r + 0.587f * g + 0.114f * bl, 0.0f), 1.0f);

        float xsf = (float)px * (15.0f / 1023.0f);
        int x0 = (int)floorf(xsf); int x1 = min(x0 + 1, 15);
        float wx = xsf - (float)x0;

        float d  = gd * 7.0f;
        int d0 = (int)floorf(d); d0 = max(0, min(d0, 7));
        int d1 = min(d0 + 1, 7);
        float wd = fminf(fmaxf(d - (float)d0, 0.0f), 1.0f);

        float co[12];
        #pragma unroll
        for (int p = 0; p < 12; ++p) co[p] = 0.0f;

        #pragma unroll
        for (int cy = 0; cy < 2; ++cy) {
            int   yy  = cy ? y1 : y0;
            float wyf = cy ? wy : 1.0f - wy;
            #pragma unroll
            for (int cx = 0; cx < 2; ++cx) {
                int   xx  = cx ? x1 : x0;
                float wyx = wyf * (cx ? wx : 1.0f - wx);
                const float* g0 = gb + ((yy * 16 + xx) * 8 + d0) * 12;
                const float* g1 = gb + ((yy * 16 + xx) * 8 + d1) * 12;
                float wA = wyx * (1.0f - wd), wB = wyx * wd;
                #pragma unroll
                for (int p = 0; p < 12; ++p) co[p] += wA * g0[p] + wB * g1[p];
            }
        }

        #pragma unroll
        for (int i = 0; i < 3; ++i) {
            float v = co[i * 4 + 0] * r + co[i * 4 + 1] * g + co[i * 4 + 2] * bl + co[i * 4 + 3];
            outv[i][s] = fminf(fmaxf(v, 0.0f), 1.0f);
        }
    }

    float* ob = out + (size_t)b * 3 * HW1K;
    #pragma unroll
    for (int i = 0; i < 3; ++i)
        *(f4*)(ob + i * HW1K + po) = outv[i];
}

// ---------------------------------------------------------------------------
extern "C" void kernel_launch(void* const* d_in, const int* in_sizes, int n_in,
                              void* d_out, int out_size, void* d_ws, size_t ws_size,
                              hipStream_t stream) {
    const float* x  = (const float*)d_in[0];
    const float* w1 = (const float*)d_in[1];  const float* b1 = (const float*)d_in[2];
    const float* w2 = (const float*)d_in[3];  const float* b2 = (const float*)d_in[4];
    const float* w3 = (const float*)d_in[5];  const float* b3 = (const float*)d_in[6];
    const float* w4 = (const float*)d_in[7];  const float* b4 = (const float*)d_in[8];
    const float* w5 = (const float*)d_in[9];  const float* b5 = (const float*)d_in[10];
    const float* w6 = (const float*)d_in[11]; const float* b6 = (const float*)d_in[12];
    float* out = (float*)d_out;

    float* wp  = (float*)d_ws;      // 124848 floats
    float* c16 = wp + 124848;       // 2*24576 floats

    prep_w<<<dim3((124848 + 255) / 256), dim3(256), 0, stream>>>(w1, w2, w3, w4, w5, w6, wp);
    fused_cone<<<dim3(16, 16, 2), dim3(512), 0, stream>>>(x, wp, b1, b2, b3, b4, b5, b6, c16);
    slice_apply4<<<dim3(2 * HW1K / 4 / 256), dim3(256), 0, stream>>>(x, c16, out);

    (void)in_sizes; (void)n_in; (void)out_size; (void)ws_size;
}

// Round 8
// 362.996 us; speedup vs baseline: 1.5729x; 1.5729x over previous
//
#include <hip/hip_runtime.h>
#include <hip/hip_bf16.h>

#define HW1K  1048576    // 1024*1024

typedef float f4 __attribute__((ext_vector_type(4)));

__device__ __forceinline__ f4 relu4(f4 v) {
    v.x = fmaxf(v.x, 0.0f); v.y = fmaxf(v.y, 0.0f);
    v.z = fmaxf(v.z, 0.0f); v.w = fmaxf(v.w, 0.0f);
    return v;
}

// Weight-prep: OIHW -> wp[layer_base + (ci*9+ky*3+kx)*COUT + co] (co fastest:
// coalesced, f4-aligned over co; all layer bases mult of 4).
// Bases: L1@0(432) L2@432(4608) L3@5040(9216) L4@14256(18432) L5@32688(36864)
// L6@69552(55296), total 124848.
__global__ void prep_w(const float* __restrict__ w1, const float* __restrict__ w2,
                       const float* __restrict__ w3, const float* __restrict__ w4,
                       const float* __restrict__ w5, const float* __restrict__ w6,
                       float* __restrict__ wp) {
    int i = blockIdx.x * 256 + threadIdx.x;
    if (i >= 124848) return;
    const float* src; int base, cin, cout;
    if      (i < 432)   { src = w1; base = 0;     cin = 3;  cout = 16; }
    else if (i < 5040)  { src = w2; base = 432;   cin = 16; cout = 32; }
    else if (i < 14256) { src = w3; base = 5040;  cin = 32; cout = 32; }
    else if (i < 32688) { src = w4; base = 14256; cin = 32; cout = 64; }
    else if (i < 69552) { src = w5; base = 32688; cin = 64; cout = 64; }
    else                { src = w6; base = 69552; cin = 64; cout = 96; }
    int r  = i - base;
    int kk = r / cout;
    int co = r % cout;
    int ci = kk / 9;
    int t9 = kk % 9;
    wp[i] = src[(co * cin + ci) * 9 + t9];
}

// ---------------------------------------------------------------------------
// Strip conv layer, 512 threads, ci-split x2: half = tid>>8 computes ci4 range
// [half*CIN/8, (half+1)*CIN/8). Raw partials (no bias/relu) -> sOut (half 0)
// and sPart (half 1); combine() adds bias, applies relu.
// Thread (within half) = (cog -> 4 output ch, strip-slot -> 1x2 px strip).
// Strides SI=CIN+4, SO=COUT+4 (16B-aligned).
template <int WIN, int CIN, int COUT, int SPT>
__device__ __forceinline__ void layer_s2(const float* __restrict__ sIn, float* __restrict__ sOut,
                                         float* __restrict__ sPart, const float* __restrict__ wp) {
    constexpr int WOUT  = WIN - 2;
    constexpr int SI    = CIN + 4;
    constexpr int SO    = COUT + 4;
    constexpr int COG   = COUT / 4;
    constexpr int SLOTS = 256 / COG;
    constexpr int HSTR  = WOUT / 2;
    constexpr int NSTR  = WOUT * HSTR;
    constexpr int NCI4  = CIN / 8;          // ci4 iterations per half

    const int tid  = threadIdx.x;
    const int half = tid >> 8;
    const int t    = tid & 255;
    const int cog  = t % COG;
    const int co0  = cog * 4;
    const int ps   = t / COG;
    const int c40  = half * NCI4;

    float* dst = half ? sPart : sOut;

    #pragma unroll
    for (int s = 0; s < SPT; ++s) {
        int ss = ps + s * SLOTS;
        if (ss > NSTR - 1) ss = NSTR - 1;          // duplicates write same value
        const int row  = ss / HSTR;
        const int col2 = (ss % HSTR) * 2;
        const int base = (row * WIN + col2) * SI;

        f4 acc0 = {0.f, 0.f, 0.f, 0.f}, acc1 = {0.f, 0.f, 0.f, 0.f};

        for (int ci4 = c40; ci4 < c40 + NCI4; ++ci4) {
            f4 a[3][4];
            #pragma unroll
            for (int r = 0; r < 3; ++r)
                #pragma unroll
                for (int c = 0; c < 4; ++c)
                    a[r][c] = *(const f4*)(sIn + base + (r * WIN + c) * SI + ci4 * 4);
            #pragma unroll
            for (int cc = 0; cc < 4; ++cc) {
                #pragma unroll
                for (int ky = 0; ky < 3; ++ky) {
                    #pragma unroll
                    for (int kx = 0; kx < 3; ++kx) {
                        f4 w = *(const f4*)(wp + ((ci4 * 4 + cc) * 9 + ky * 3 + kx) * COUT + co0);
                        acc0 += w * a[ky][kx][cc];
                        acc1 += w * a[ky][kx + 1][cc];
                    }
                }
            }
        }
        const int opx = row * WOUT + col2;
        *(f4*)(dst + opx * SO + co0)       = acc0;
        *(f4*)(dst + (opx + 1) * SO + co0) = acc1;
    }
}

// Single-px variant (L5: 16 px x 16 cog = 256 per half), ci-split x2.
template <int WIN, int CIN, int COUT>
__device__ __forceinline__ void layer_p2(const float* __restrict__ sIn, float* __restrict__ sOut,
                                         float* __restrict__ sPart, const float* __restrict__ wp) {
    constexpr int WOUT = WIN - 2;
    constexpr int SI   = CIN + 4;
    constexpr int SO   = COUT + 4;
    constexpr int COG  = COUT / 4;
    constexpr int NCI4 = CIN / 8;

    const int tid  = threadIdx.x;
    const int half = tid >> 8;
    const int t    = tid & 255;
    const int cog  = t % COG;
    const int co0  = cog * 4;
    const int px   = t / COG;
    const int row  = px / WOUT, col = px % WOUT;
    const int base = (row * WIN + col) * SI;
    const int c40  = half * NCI4;

    f4 acc = {0.f, 0.f, 0.f, 0.f};

    for (int ci4 = c40; ci4 < c40 + NCI4; ++ci4) {
        f4 a[3][3];
        #pragma unroll
        for (int r = 0; r < 3; ++r)
            #pragma unroll
            for (int c = 0; c < 3; ++c)
                a[r][c] = *(const f4*)(sIn + base + (r * WIN + c) * SI + ci4 * 4);
        #pragma unroll
        for (int cc = 0; cc < 4; ++cc)
            #pragma unroll
            for (int k = 0; k < 9; ++k) {
                f4 w = *(const f4*)(wp + ((ci4 * 4 + cc) * 9 + k) * COUT + co0);
                acc += w * a[k / 3][k % 3][cc];
            }
    }
    float* dst = half ? sPart : sOut;
    *(f4*)(dst + px * SO + co0) = acc;
}

// Combine halves: out = relu(p0 + p1 + bias). In-place on sOut.
template <int NPX, int COUT, int RELU>
__device__ __forceinline__ void combine(float* __restrict__ sOut, const float* __restrict__ sPart,
                                        const float* __restrict__ bias) {
    constexpr int SO  = COUT + 4;
    constexpr int COG = COUT / 4;
    for (int i = threadIdx.x; i < NPX * COG; i += 512) {
        int px = i / COG, co0 = (i % COG) * 4;
        f4 v = *(const f4*)(sOut + px * SO + co0) + *(const f4*)(sPart + px * SO + co0)
             + *(const f4*)(bias + co0);
        if (RELU) v = relu4(v);
        *(f4*)(sOut + px * SO + co0) = v;
    }
}

// ---------------------------------------------------------------------------
// Fully fused per-grid-cell pipeline, block = (gx, gy, b), 512 threads.
// 14x14x3 cone -> conv1..6 (VALID 14->12->10->8->6->4->2) -> 2x2 pool ->
// c16[b][gy*16+gx][d][p]. Cone coords in [1,254]: padding never triggers.
// launch_bounds (512,2): 2 blocks/CU (16 waves/CU), VGPR cap >=128 -> no
// spill (R7's (512,4) forced a 64-VGPR cap -> 865 MB scratch traffic).
__global__ __launch_bounds__(512, 2)
void fused_cone(const float* __restrict__ x, const float* __restrict__ wp,
                const float* __restrict__ b1, const float* __restrict__ b2,
                const float* __restrict__ b3, const float* __restrict__ b4,
                const float* __restrict__ b5, const float* __restrict__ b6,
                float* __restrict__ c16) {
    __shared__ float sA[3600];   // xin 784 / t2 3600 / t4 2448 / L6 part 1536
    __shared__ float sB[2880];   // t1 2880 / t3 2304 / t5 1088
    __shared__ float sC[3600];   // ci-split partials

    const int gx = blockIdx.x, gy = blockIdx.y, b = blockIdx.z;
    const float* xb = x + (size_t)b * 3 * HW1K;

    // xin: xlow cone [14*14][stride 4]; xlow[y][x] = avg of x rows 4y+1..4y+2,
    // cols 4x+1..4x+2 (exact bilinear 4x downsample).
    for (int i = threadIdx.x; i < 588; i += 512) {
        int c  = i % 3;
        int t  = i / 3;
        int xi = t % 14;
        int yi = t / 14;
        int ya = 16 * gy + 1 + yi;
        int xa = 16 * gx + 1 + xi;
        const float* p = xb + (size_t)c * HW1K + (4 * ya + 1) * 1024 + (4 * xa + 1);
        sA[t * 4 + c] = 0.25f * (p[0] + p[1] + p[1024] + p[1025]);
    }
    __syncthreads();

    // L1: CIN=3 (scalar act reads), 512 threads: cog=tid%4, 128 px-slots x2.
    // Bias+relu inline (no split). out t1 [144][20].
    {
        const int cog = threadIdx.x % 4, co0 = cog * 4, ps = threadIdx.x / 4;
        const f4 bs = *(const f4*)(b1 + co0);
        f4 acc[2]; int base[2], pxc[2];
        #pragma unroll
        for (int pp = 0; pp < 2; ++pp) {
            int px = ps + pp * 128; if (px > 143) px = 143;
            pxc[pp]  = px;
            base[pp] = ((px / 12) * 14 + (px % 12)) * 4;
            acc[pp]  = bs;
        }
        for (int ci = 0; ci < 3; ++ci) {
            #pragma unroll
            for (int k = 0; k < 9; ++k) {
                f4 w = *(const f4*)(wp + (ci * 9 + k) * 16 + co0);
                int off = ((k / 3) * 14 + (k % 3)) * 4 + ci;
                #pragma unroll
                for (int pp = 0; pp < 2; ++pp)
                    acc[pp] += w * sA[base[pp] + off];
            }
        }
        #pragma unroll
        for (int pp = 0; pp < 2; ++pp)
            *(f4*)(sB + pxc[pp] * 20 + co0) = relu4(acc[pp]);
    }
    __syncthreads();

    layer_s2<12, 16, 32, 2>(sB, sA, sC, wp + 432);   __syncthreads();
    combine<100, 32, 1>(sA, sC, b2);                 __syncthreads();  // t2 [100][36]
    layer_s2<10, 32, 32, 1>(sA, sB, sC, wp + 5040);  __syncthreads();
    combine<64, 32, 1>(sB, sC, b3);                  __syncthreads();  // t3 [64][36]
    layer_s2< 8, 32, 64, 2>(sB, sA, sC, wp + 14256); __syncthreads();
    combine<36, 64, 1>(sA, sC, b4);                  __syncthreads();  // t4 [36][68]
    layer_p2< 6, 64, 64>(sA, sB, sC, wp + 32688);    __syncthreads();
    combine<16, 64, 1>(sB, sC, b5);                  __syncthreads();  // t5 [16][68]

    // L6: CIN=64, COUT=96, WIN=4->WOUT=2 (4 px), ci-split x4 (quarters).
    // Active: 4*96 threads; raw partials -> sA [quarter][4px][96]; no relu.
    {
        const int q = threadIdx.x >> 7;
        const int r = threadIdx.x & 127;
        if (r < 96) {
            const int cog = r % 24, co0 = cog * 4, px = r / 24;
            const int base = ((px >> 1) * 4 + (px & 1)) * 68;
            f4 acc = {0.f, 0.f, 0.f, 0.f};
            for (int ci4 = q * 4; ci4 < q * 4 + 4; ++ci4) {
                f4 a[3][3];
                #pragma unroll
                for (int rr = 0; rr < 3; ++rr)
                    #pragma unroll
                    for (int c = 0; c < 3; ++c)
                        a[rr][c] = *(const f4*)(sB + base + (rr * 4 + c) * 68 + ci4 * 4);
                #pragma unroll
                for (int cc = 0; cc < 4; ++cc)
                    #pragma unroll
                    for (int k = 0; k < 9; ++k) {
                        f4 w = *(const f4*)(wp + 69552 + ((ci4 * 4 + cc) * 9 + k) * 96 + co0);
                        acc += w * a[k / 3][k % 3][cc];
                    }
            }
            *(f4*)(sA + q * 384 + px * 96 + co0) = acc;
        }
    }
    __syncthreads();

    // pool 2x2 (exact 16x bilinear downsample) + combine quarters + bias.
    if (threadIdx.x < 96) {
        const int ch = threadIdx.x;
        float v = 0.0f;
        #pragma unroll
        for (int q = 0; q < 4; ++q)
            #pragma unroll
            for (int px = 0; px < 4; ++px)
                v += sA[q * 384 + px * 96 + ch];
        v = 0.25f * v + b6[ch];
        int p = ch >> 3, d = ch & 7;
        c16[(size_t)b * 24576 + ((gy * 16 + gx) * 8 + d) * 12 + p] = v;
    }
}

// ---------------------------------------------------------------------------
// Fused guide + trilinear slice + affine + clip; 4 px per thread (float4).
// c16 layout: [b][gy*16+gx][d][p=12].
__global__ __launch_bounds__(256)
void slice_apply4(const float* __restrict__ x, const float* __restrict__ c16,
                  float* __restrict__ out) {
    int t = blockIdx.x * 256 + threadIdx.x;      // 0 .. 2*HW1K/4 - 1
    int po4 = t * 4;
    int b   = po4 >> 20;
    int po  = po4 & (HW1K - 1);
    int py  = po >> 10;
    int px0 = po & 1023;

    const float* xb = x + (size_t)b * 3 * HW1K;
    f4 rv  = *(const f4*)(xb + po);
    f4 gv  = *(const f4*)(xb + HW1K + po);
    f4 bv  = *(const f4*)(xb + 2 * HW1K + po);

    float ysf = (float)py * (15.0f / 1023.0f);
    int y0 = (int)floorf(ysf); int y1 = min(y0 + 1, 15);
    float wy = ysf - (float)y0;

    const float* gb = c16 + (size_t)b * 24576;
    f4 outv[3];

    #pragma unroll
    for (int s = 0; s < 4; ++s) {
        float r  = rv[s], g = gv[s], bl = bv[s];
        int   px = px0 + s;

        float gd = fminf(fmaxf(0.299f * r + 0.587f * g + 0.114f * bl, 0.0f), 1.0f);

        float xsf = (float)px * (15.0f / 1023.0f);
        int x0 = (int)floorf(xsf); int x1 = min(x0 + 1, 15);
        float wx = xsf - (float)x0;

        float d  = gd * 7.0f;
        int d0 = (int)floorf(d); d0 = max(0, min(d0, 7));
        int d1 = min(d0 + 1, 7);
        float wd = fminf(fmaxf(d - (float)d0, 0.0f), 1.0f);

        float co[12];
        #pragma unroll
        for (int p = 0; p < 12; ++p) co[p] = 0.0f;

        #pragma unroll
        for (int cy = 0; cy < 2; ++cy) {
            int   yy  = cy ? y1 : y0;
            float wyf = cy ? wy : 1.0f - wy;
            #pragma unroll
            for (int cx = 0; cx < 2; ++cx) {
                int   xx  = cx ? x1 : x0;
                float wyx = wyf * (cx ? wx : 1.0f - wx);
                const float* g0 = gb + ((yy * 16 + xx) * 8 + d0) * 12;
                const float* g1 = gb + ((yy * 16 + xx) * 8 + d1) * 12;
                float wA = wyx * (1.0f - wd), wB = wyx * wd;
                #pragma unroll
                for (int p = 0; p < 12; ++p) co[p] += wA * g0[p] + wB * g1[p];
            }
        }

        #pragma unroll
        for (int i = 0; i < 3; ++i) {
            float v = co[i * 4 + 0] * r + co[i * 4 + 1] * g + co[i * 4 + 2] * bl + co[i * 4 + 3];
            outv[i][s] = fminf(fmaxf(v, 0.0f), 1.0f);
        }
    }

    float* ob = out + (size_t)b * 3 * HW1K;
    #pragma unroll
    for (int i = 0; i < 3; ++i)
        *(f4*)(ob + i * HW1K + po) = outv[i];
}

// ---------------------------------------------------------------------------
extern "C" void kernel_launch(void* const* d_in, const int* in_sizes, int n_in,
                              void* d_out, int out_size, void* d_ws, size_t ws_size,
                              hipStream_t stream) {
    const float* x  = (const float*)d_in[0];
    const float* w1 = (const float*)d_in[1];  const float* b1 = (const float*)d_in[2];
    const float* w2 = (const float*)d_in[3];  const float* b2 = (const float*)d_in[4];
    const float* w3 = (const float*)d_in[5];  const float* b3 = (const float*)d_in[6];
    const float* w4 = (const float*)d_in[7];  const float* b4 = (const float*)d_in[8];
    const float* w5 = (const float*)d_in[9];  const float* b5 = (const float*)d_in[10];
    const float* w6 = (const float*)d_in[11]; const float* b6 = (const float*)d_in[12];
    float* out = (float*)d_out;

    float* wp  = (float*)d_ws;      // 124848 floats
    float* c16 = wp + 124848;       // 2*24576 floats

    prep_w<<<dim3((124848 + 255) / 256), dim3(256), 0, stream>>>(w1, w2, w3, w4, w5, w6, wp);
    fused_cone<<<dim3(16, 16, 2), dim3(512), 0, stream>>>(x, wp, b1, b2, b3, b4, b5, b6, c16);
    slice_apply4<<<dim3(2 * HW1K / 4 / 256), dim3(256), 0, stream>>>(x, c16, out);

    (void)in_sizes; (void)n_in; (void)out_size; (void)ws_size;
}